// Round 5
// baseline (692.967 us; speedup 1.0000x reference)
//
#include <hip/hip_runtime.h>
#include <hip/hip_bf16.h>

#define HIDDEN 128
#define NRAD 6

typedef short bf16x8 __attribute__((ext_vector_type(8)));
typedef short bf16x4 __attribute__((ext_vector_type(4)));
typedef float f32x4 __attribute__((ext_vector_type(4)));

__device__ __forceinline__ float swishf(float z) {
    return z / (1.0f + __expf(-z));
}

__device__ __forceinline__ unsigned short f2bf(float f) {
    unsigned int u = __float_as_uint(f);
    unsigned int r = (u + 0x7FFFu + ((u >> 16) & 1u)) >> 16;
    return (unsigned short)r;
}

__device__ __forceinline__ float bf2f(unsigned int s) {
    return __uint_as_float(s << 16);
}

__device__ __forceinline__ unsigned int pk2bf(float x, float y) {
    __hip_bfloat162 h = __float22bfloat162_rn(make_float2(x, y));
    return *reinterpret_cast<unsigned int*>(&h);
}

__device__ __forceinline__ f32x4 fmav(float s, f32x4 w, f32x4 z) {
    z[0] += s * w[0]; z[1] += s * w[1]; z[2] += s * w[2]; z[3] += s * w[3];
    return z;
}

// ---------------------------------------------------------------------------
// Kernel 1: T1 = emb_table @ W1 + b (bias folded here), T3 = emb_table @ W3
// ---------------------------------------------------------------------------
__global__ void k_emb_proj(const float* __restrict__ emb, const float* __restrict__ W,
                           const float* __restrict__ bvec,
                           float* __restrict__ T1, float* __restrict__ T3,
                           float* __restrict__ out_scalar) {
    int v = blockIdx.x;
    int h = threadIdx.x;
    if (v == 0 && h == 0) *out_scalar = 1.0f;
    const float* er = emb + v * HIDDEN;
    float a1 = bvec[h], a3 = 0.f;
    #pragma unroll 4
    for (int k = 0; k < HIDDEN; ++k) {
        float e = er[k];
        a1 += e * W[k * HIDDEN + h];
        a3 += e * W[(256 + k) * HIDDEN + h];
    }
    T1[v * HIDDEN + h] = a1;
    T3[v * HIDDEN + h] = a3;
}

// ---------------------------------------------------------------------------
// Kernel 1b: repack W2, W4, W5 into bf16 MFMA A-operand fragments of W^T.
// ---------------------------------------------------------------------------
__global__ void k_wprep(const float* __restrict__ W, short* __restrict__ wf) {
    int gid = blockIdx.x * 256 + threadIdx.x;   // 0..6143
    int m = gid >> 11;
    int t = gid & 2047;
    int l = t & 63;
    int tile = t >> 6;
    int n = tile >> 2, kt = tile & 3;
    int k0 = kt * 32 + (l >> 4) * 8;
    int col = n * 16 + (l & 15);
    static const int rowoff[3] = {128, 384, 512};   // W2, W4, W5
    const float* Wm = W + rowoff[m] * HIDDEN;
    bf16x8 v;
    #pragma unroll
    for (int j = 0; j < 8; ++j) v[j] = (short)f2bf(Wm[(k0 + j) * HIDDEN + col]);
    *(bf16x8*)(wf + (size_t)gid * 8) = v;
}

// ---------------------------------------------------------------------------
// Kernel 2 (MFMA): A[n] = T1[x[n]] + chi[n]@W2 ; B[n] = T3[x[n]] + chi[n]@W4
// (T1 already contains bias b.)
// ---------------------------------------------------------------------------
#define NB 64
__global__ __launch_bounds__(256) void k_node(const int* __restrict__ x,
        const float* __restrict__ chi,
        const short* __restrict__ w2f, const short* __restrict__ w4f,
        const float* __restrict__ T1, const float* __restrict__ T3,
        short* __restrict__ Abf, short* __restrict__ Bbf, int n_nodes) {
    __shared__ unsigned short chi_s[NB * HIDDEN];
    __shared__ int x_s[NB];
    int n0 = blockIdx.x * NB;
    int t = threadIdx.x;
    int l = t & 63;
    int wv = t >> 6;

    #pragma unroll
    for (int it = 0; it < 8; ++it) {
        int q = t + it * 256;
        int row = q >> 5, s = q & 31;
        int gn = n0 + row;
        float4 c = (gn < n_nodes) ? *(const float4*)(chi + (size_t)gn * HIDDEN + s * 4)
                                  : make_float4(0.f, 0.f, 0.f, 0.f);
        unsigned int lo = pk2bf(c.x, c.y), hi = pk2bf(c.z, c.w);
        unsigned int byte = (unsigned int)(row * 256 + s * 8) ^ ((row & 7) << 4);
        *(uint2*)((char*)chi_s + byte) = make_uint2(lo, hi);
    }
    if (t < NB) {
        int gn = n0 + t;
        x_s[t] = (gn < n_nodes) ? x[gn] : 0;
    }
    __syncthreads();

    bf16x8 cfrag[4];
    {
        int rloc = wv * 16 + (l & 15);
        unsigned int base = (unsigned int)(rloc * 256 + (l >> 4) * 16);
        unsigned int swz = (unsigned int)((rloc & 7) << 4);
        #pragma unroll
        for (int kt = 0; kt < 4; ++kt)
            cfrag[kt] = *(const bf16x8*)((const char*)chi_s + ((base + kt * 64) ^ swz));
    }

    int nd_loc = wv * 16 + (l & 15);
    int gn = n0 + nd_loc;
    int xv = x_s[nd_loc];
    int hq = (l >> 4) * 4;

    #pragma unroll
    for (int n = 0; n < 8; ++n) {
        f32x4 aA = {0.f, 0.f, 0.f, 0.f};
        f32x4 aB = {0.f, 0.f, 0.f, 0.f};
        #pragma unroll
        for (int kt = 0; kt < 4; ++kt) {
            bf16x8 w2 = *(const bf16x8*)(w2f + ((size_t)(n * 4 + kt) * 64 + l) * 8);
            bf16x8 w4 = *(const bf16x8*)(w4f + ((size_t)(n * 4 + kt) * 64 + l) * 8);
            aA = __builtin_amdgcn_mfma_f32_16x16x32_bf16(w2, cfrag[kt], aA, 0, 0, 0);
            aB = __builtin_amdgcn_mfma_f32_16x16x32_bf16(w4, cfrag[kt], aB, 0, 0, 0);
        }
        if (gn < n_nodes) {
            int h = n * 16 + hq;
            float4 t1 = *(const float4*)(T1 + (size_t)xv * HIDDEN + h);
            float4 t3 = *(const float4*)(T3 + (size_t)xv * HIDDEN + h);
            unsigned int a0 = pk2bf(aA[0] + t1.x, aA[1] + t1.y);
            unsigned int a1 = pk2bf(aA[2] + t1.z, aA[3] + t1.w);
            unsigned int b0 = pk2bf(aB[0] + t3.x, aB[1] + t3.y);
            unsigned int b1 = pk2bf(aB[2] + t3.z, aB[3] + t3.w);
            *(uint2*)(Abf + (size_t)gn * HIDDEN + h) = make_uint2(a0, a1);
            *(uint2*)(Bbf + (size_t)gn * HIDDEN + h) = make_uint2(b0, b1);
        }
    }
}

// ---------------------------------------------------------------------------
// Kernel 3: persistent-wave edge kernel, barrier-free main loop.
// Wave owns a 16-edge tile; W5 fragments register-resident (128 VGPR);
// phase-1 weights read from LDS (lgkmcnt) so the A/B gather queue (vmcnt)
// is never drained mid-tile. Wave-private LDS transpose for full-line stores.
// ---------------------------------------------------------------------------
#define KE_BLOCKS 512
#define SEGDW (16 * 68)      // 16 rows x 68 dwords (68 = 64 + 4 pad -> bank rotate)
__global__ __launch_bounds__(256, 2) void k_edge(
        const float* __restrict__ rbf,
        const int* __restrict__ ei, const int* __restrict__ ej,
        const float* __restrict__ W_rbf, const float* __restrict__ b_rbf,
        const short* __restrict__ w5f,
        const short* __restrict__ Abf, const short* __restrict__ Bbf,
        float* __restrict__ out, int n_edges, int n_tiles, int n_waves) {
    __shared__ float wrb_s[7 * HIDDEN];     // rows 0..5 = W_rbf, row 6 = b_rbf
    __shared__ float seg_s[4 * SEGDW];      // per-wave transpose buffers

    int t = threadIdx.x;
    int l = t & 63;
    int wv = t >> 6;

    for (int q = t; q < 7 * HIDDEN; q += 256)
        wrb_s[q] = (q < 6 * HIDDEN) ? W_rbf[q] : b_rbf[q - 6 * HIDDEN];
    __syncthreads();   // only barrier; main loop below is barrier-free

    // W5 fragments -> registers (once per wave)
    bf16x8 w5r[32];
    #pragma unroll
    for (int f = 0; f < 32; ++f)
        w5r[f] = *(const bf16x8*)(w5f + ((size_t)f * 64 + l) * 8);

    int g = l >> 4;          // h-group
    int er = l & 15;         // edge row within tile
    float* seg = seg_s + wv * SEGDW;

    int tile = blockIdx.x * 4 + wv;
    if (tile >= n_tiles) return;

    // prologue prefetch for first tile
    int e_pf = min(tile * 16 + er, n_edges - 1);
    int iv_n = ei[e_pf], jv_n = ej[e_pf];
    float2 r01_n = *(const float2*)(rbf + (size_t)e_pf * NRAD);
    float2 r23_n = *(const float2*)(rbf + (size_t)e_pf * NRAD + 2);
    float2 r45_n = *(const float2*)(rbf + (size_t)e_pf * NRAD + 4);

    for (; tile < n_tiles; tile += n_waves) {
        int e_base = tile * 16;
        int iv = iv_n, jv = jv_n;
        float rb0 = r01_n.x, rb1 = r01_n.y, rb2 = r23_n.x,
              rb3 = r23_n.y, rb4 = r45_n.x, rb5 = r45_n.y;

        // issue A/B gathers for this tile (consumed in epilogue)
        const short* ap = Abf + (size_t)iv * HIDDEN + g * 4;
        const short* bp = Bbf + (size_t)jv * HIDDEN + g * 4;
        uint2 avu[8], bvu[8];
        #pragma unroll
        for (int n = 0; n < 8; ++n) {
            avu[n] = *(const uint2*)(ap + n * 16);
            bvu[n] = *(const uint2*)(bp + n * 16);
        }

        // prefetch next tile's idx + rbf
        int tn = tile + n_waves;
        int e_next = (tn < n_tiles) ? min(tn * 16 + er, n_edges - 1) : (n_edges - 1);
        iv_n = ei[e_next]; jv_n = ej[e_next];
        r01_n = *(const float2*)(rbf + (size_t)e_next * NRAD);
        r23_n = *(const float2*)(rbf + (size_t)e_next * NRAD + 2);
        r45_n = *(const float2*)(rbf + (size_t)e_next * NRAD + 4);

        // phase-1: P[er][h] = swish(rbf . W_rbf + b_rbf), h = kt*32 + g*8 + j
        bf16x8 pfrag[4];
        #pragma unroll
        for (int kt = 0; kt < 4; ++kt) {
            int cb = kt * 32 + g * 8;
            f32x4 z0 = *(const f32x4*)(wrb_s + 6 * HIDDEN + cb);
            f32x4 z1 = *(const f32x4*)(wrb_s + 6 * HIDDEN + cb + 4);
            #pragma unroll
            for (int r = 0; r < 6; ++r) {
                float s = (r == 0) ? rb0 : (r == 1) ? rb1 : (r == 2) ? rb2
                        : (r == 3) ? rb3 : (r == 4) ? rb4 : rb5;
                z0 = fmav(s, *(const f32x4*)(wrb_s + r * HIDDEN + cb), z0);
                z1 = fmav(s, *(const f32x4*)(wrb_s + r * HIDDEN + cb + 4), z1);
            }
            union { bf16x8 v; unsigned int u[4]; } pu;
            pu.u[0] = pk2bf(swishf(z0[0]), swishf(z0[1]));
            pu.u[1] = pk2bf(swishf(z0[2]), swishf(z0[3]));
            pu.u[2] = pk2bf(swishf(z1[0]), swishf(z1[1]));
            pu.u[3] = pk2bf(swishf(z1[2]), swishf(z1[3]));
            pfrag[kt] = pu.v;
        }

        bool full = (e_base + 16 <= n_edges);
        #pragma unroll
        for (int sgi = 0; sgi < 2; ++sgi) {
            f32x4 acc[4];
            #pragma unroll
            for (int nn = 0; nn < 4; ++nn) {
                int n = sgi * 4 + nn;
                f32x4 a = {0.f, 0.f, 0.f, 0.f};
                #pragma unroll
                for (int kt = 0; kt < 4; ++kt)
                    a = __builtin_amdgcn_mfma_f32_16x16x32_bf16(w5r[n * 4 + kt], pfrag[kt], a, 0, 0, 0);
                acc[nn] = a;
            }
            #pragma unroll
            for (int nn = 0; nn < 4; ++nn) {
                int n = sgi * 4 + nn;
                uint2 au = avu[n], bu = bvu[n];
                f32x4 o;
                o[0] = swishf(acc[nn][0] + bf2f(au.x & 0xffffu) + bf2f(bu.x & 0xffffu));
                o[1] = swishf(acc[nn][1] + bf2f(au.x >> 16) + bf2f(bu.x >> 16));
                o[2] = swishf(acc[nn][2] + bf2f(au.y & 0xffffu) + bf2f(bu.y & 0xffffu));
                o[3] = swishf(acc[nn][3] + bf2f(au.y >> 16) + bf2f(bu.y >> 16));
                if (full) {
                    *(f32x4*)(seg + er * 68 + nn * 16 + g * 4) = o;
                } else if (e_base + er < n_edges) {
                    *(f32x4*)(out + (size_t)(e_base + er) * HIDDEN + n * 16 + g * 4) = o;
                }
            }
            if (full) {
                #pragma unroll
                for (int i2 = 0; i2 < 4; ++i2) {
                    f32x4 v = *(const f32x4*)(seg + (l >> 2) * 68 + i2 * 16 + (l & 3) * 4);
                    float* dst = out + (size_t)(e_base + (l >> 2)) * HIDDEN
                               + sgi * 64 + i2 * 16 + (l & 3) * 4;
                    __builtin_nontemporal_store(v, (f32x4*)dst);
                }
            }
        }
    }
}

extern "C" void kernel_launch(void* const* d_in, const int* in_sizes, int n_in,
                              void* d_out, int out_size, void* d_ws, size_t ws_size,
                              hipStream_t stream) {
    const int*   x     = (const int*)d_in[0];
    const float* chi   = (const float*)d_in[1];
    const float* rbf   = (const float*)d_in[2];
    const int*   ei    = (const int*)d_in[3];
    const int*   ej    = (const int*)d_in[4];
    const float* emb   = (const float*)d_in[5];
    const float* W_rbf = (const float*)d_in[6];
    const float* b_rbf = (const float*)d_in[7];
    const float* W     = (const float*)d_in[8];
    const float* bvec  = (const float*)d_in[9];
    float* out = (float*)d_out;

    int n_nodes = in_sizes[0];
    int n_edges = in_sizes[3];
    int vocab   = in_sizes[5] / HIDDEN;

    short* Abf = (short*)d_ws;
    short* Bbf = Abf + (size_t)n_nodes * HIDDEN;
    float* T1  = (float*)(Bbf + (size_t)n_nodes * HIDDEN);
    float* T3  = T1 + (size_t)vocab * HIDDEN;
    short* wf  = (short*)(T3 + (size_t)vocab * HIDDEN);
    short* w2f = wf;
    short* w4f = wf + 16384;
    short* w5f = wf + 32768;

    int n_tiles = (n_edges + 15) / 16;
    int n_waves = KE_BLOCKS * 4;

    k_emb_proj<<<vocab, HIDDEN, 0, stream>>>(emb, W, bvec, T1, T3, out + (out_size - 1));
    k_wprep<<<24, 256, 0, stream>>>(W, wf);
    k_node<<<(n_nodes + NB - 1) / NB, 256, 0, stream>>>(x, chi, w2f, w4f, T1, T3,
                                                        Abf, Bbf, n_nodes);
    k_edge<<<KE_BLOCKS, 256, 0, stream>>>(rbf, ei, ej, W_rbf, b_rbf,
                                          w5f, Abf, Bbf, out, n_edges, n_tiles, n_waves);
}

// Round 7
// 234.933 us; speedup vs baseline: 2.9496x; 2.9496x over previous
//
#include <hip/hip_runtime.h>
#include <hip/hip_bf16.h>

#define HIDDEN 128
#define NRAD 6

typedef short bf16x8 __attribute__((ext_vector_type(8)));
typedef float f32x4 __attribute__((ext_vector_type(4)));

__device__ __forceinline__ float swishf(float z) {
    return z / (1.0f + __expf(-z));
}

__device__ __forceinline__ unsigned short f2bf(float f) {
    unsigned int u = __float_as_uint(f);
    unsigned int r = (u + 0x7FFFu + ((u >> 16) & 1u)) >> 16;
    return (unsigned short)r;
}

__device__ __forceinline__ float bf2f(unsigned int s) {
    return __uint_as_float(s << 16);
}

__device__ __forceinline__ unsigned int pk2bf(float x, float y) {
    __hip_bfloat162 h = __float22bfloat162_rn(make_float2(x, y));
    return *reinterpret_cast<unsigned int*>(&h);
}

__device__ __forceinline__ f32x4 fmav(float s, f32x4 w, f32x4 z) {
    z[0] += s * w[0]; z[1] += s * w[1]; z[2] += s * w[2]; z[3] += s * w[3];
    return z;
}

// ---------------------------------------------------------------------------
// Kernel 1: T1 = emb_table @ W1 + b (bias folded), T3 = emb_table @ W3
// ---------------------------------------------------------------------------
__global__ void k_emb_proj(const float* __restrict__ emb, const float* __restrict__ W,
                           const float* __restrict__ bvec,
                           float* __restrict__ T1, float* __restrict__ T3,
                           float* __restrict__ out_scalar) {
    int v = blockIdx.x;
    int h = threadIdx.x;
    if (v == 0 && h == 0) *out_scalar = 1.0f;
    const float* er = emb + v * HIDDEN;
    float a1 = bvec[h], a3 = 0.f;
    #pragma unroll 4
    for (int k = 0; k < HIDDEN; ++k) {
        float e = er[k];
        a1 += e * W[k * HIDDEN + h];
        a3 += e * W[(256 + k) * HIDDEN + h];
    }
    T1[v * HIDDEN + h] = a1;
    T3[v * HIDDEN + h] = a3;
}

// ---------------------------------------------------------------------------
// Kernel 1b: repack W2, W4, W5 into bf16 MFMA A-operand fragments of W^T.
// ---------------------------------------------------------------------------
__global__ void k_wprep(const float* __restrict__ W, short* __restrict__ wf) {
    int gid = blockIdx.x * 256 + threadIdx.x;   // 0..6143
    int m = gid >> 11;
    int t = gid & 2047;
    int l = t & 63;
    int tile = t >> 6;
    int n = tile >> 2, kt = tile & 3;
    int k0 = kt * 32 + (l >> 4) * 8;
    int col = n * 16 + (l & 15);
    static const int rowoff[3] = {128, 384, 512};   // W2, W4, W5
    const float* Wm = W + rowoff[m] * HIDDEN;
    bf16x8 v;
    #pragma unroll
    for (int j = 0; j < 8; ++j) v[j] = (short)f2bf(Wm[(k0 + j) * HIDDEN + col]);
    *(bf16x8*)(wf + (size_t)gid * 8) = v;
}

// ---------------------------------------------------------------------------
// Kernel 2 (MFMA): A[n] = T1[x[n]] + chi[n]@W2 ; B[n] = T3[x[n]] + chi[n]@W4
// (T1 already contains bias b.)
// ---------------------------------------------------------------------------
#define NB 64
__global__ __launch_bounds__(256) void k_node(const int* __restrict__ x,
        const float* __restrict__ chi,
        const short* __restrict__ w2f, const short* __restrict__ w4f,
        const float* __restrict__ T1, const float* __restrict__ T3,
        short* __restrict__ Abf, short* __restrict__ Bbf, int n_nodes) {
    __shared__ unsigned short chi_s[NB * HIDDEN];
    __shared__ int x_s[NB];
    int n0 = blockIdx.x * NB;
    int t = threadIdx.x;
    int l = t & 63;
    int wv = t >> 6;

    #pragma unroll
    for (int it = 0; it < 8; ++it) {
        int q = t + it * 256;
        int row = q >> 5, s = q & 31;
        int gn = n0 + row;
        float4 c = (gn < n_nodes) ? *(const float4*)(chi + (size_t)gn * HIDDEN + s * 4)
                                  : make_float4(0.f, 0.f, 0.f, 0.f);
        unsigned int lo = pk2bf(c.x, c.y), hi = pk2bf(c.z, c.w);
        unsigned int byte = (unsigned int)(row * 256 + s * 8) ^ ((row & 7) << 4);
        *(uint2*)((char*)chi_s + byte) = make_uint2(lo, hi);
    }
    if (t < NB) {
        int gn = n0 + t;
        x_s[t] = (gn < n_nodes) ? x[gn] : 0;
    }
    __syncthreads();

    bf16x8 cfrag[4];
    {
        int rloc = wv * 16 + (l & 15);
        unsigned int base = (unsigned int)(rloc * 256 + (l >> 4) * 16);
        unsigned int swz = (unsigned int)((rloc & 7) << 4);
        #pragma unroll
        for (int kt = 0; kt < 4; ++kt)
            cfrag[kt] = *(const bf16x8*)((const char*)chi_s + ((base + kt * 64) ^ swz));
    }

    int nd_loc = wv * 16 + (l & 15);
    int gn = n0 + nd_loc;
    int xv = x_s[nd_loc];
    int hq = (l >> 4) * 4;

    #pragma unroll
    for (int n = 0; n < 8; ++n) {
        f32x4 aA = {0.f, 0.f, 0.f, 0.f};
        f32x4 aB = {0.f, 0.f, 0.f, 0.f};
        #pragma unroll
        for (int kt = 0; kt < 4; ++kt) {
            bf16x8 w2 = *(const bf16x8*)(w2f + ((size_t)(n * 4 + kt) * 64 + l) * 8);
            bf16x8 w4 = *(const bf16x8*)(w4f + ((size_t)(n * 4 + kt) * 64 + l) * 8);
            aA = __builtin_amdgcn_mfma_f32_16x16x32_bf16(w2, cfrag[kt], aA, 0, 0, 0);
            aB = __builtin_amdgcn_mfma_f32_16x16x32_bf16(w4, cfrag[kt], aB, 0, 0, 0);
        }
        if (gn < n_nodes) {
            int h = n * 16 + hq;
            float4 t1 = *(const float4*)(T1 + (size_t)xv * HIDDEN + h);
            float4 t3 = *(const float4*)(T3 + (size_t)xv * HIDDEN + h);
            unsigned int a0 = pk2bf(aA[0] + t1.x, aA[1] + t1.y);
            unsigned int a1 = pk2bf(aA[2] + t1.z, aA[3] + t1.w);
            unsigned int b0 = pk2bf(aB[0] + t3.x, aB[1] + t3.y);
            unsigned int b1 = pk2bf(aB[2] + t3.z, aB[3] + t3.w);
            *(uint2*)(Abf + (size_t)gn * HIDDEN + h) = make_uint2(a0, a1);
            *(uint2*)(Bbf + (size_t)gn * HIDDEN + h) = make_uint2(b0, b1);
        }
    }
}

// ---------------------------------------------------------------------------
// Kernel 3: 64 edges/block, 4 waves, 2 barriers.
// LDS layout (one aliased arena, 39424 B):
//   [0, 32768)      W5 fragments (bf16) -- dead after MFMA phase
//   [0, 33792)      after barrier2: per-wave seg buffers, wv*8448, 528-B rows
//   [33792, 37376)  W_rbf rows 0..5 + b_rbf (7*128 f32)
//   [37376, 38912)  rbf tile (64 x 6 f32)
//   [38912, 39424)  i_s, j_s (64+64 int)
// Gathers issued right after barrier1; consumed after barrier2 (hidden under
// phase-1 VALU + 32 MFMA). 528-B seg row stride => conflict-free b128 LDS
// writes AND reads (even 8-lane/slot spread), full 128-B-line NT stores.
// ---------------------------------------------------------------------------
#define EB 64
__global__ __launch_bounds__(256) void k_edge(const float* __restrict__ rbf,
        const int* __restrict__ ei, const int* __restrict__ ej,
        const float* __restrict__ W_rbf, const float* __restrict__ b_rbf,
        const short* __restrict__ w5f,
        const short* __restrict__ Abf, const short* __restrict__ Bbf,
        float* __restrict__ out, int n_edges) {
    __shared__ uint4 smem4[39424 / 16];
    char* base = (char*)smem4;
    short* w5_s  = (short*)base;
    float* wrb_s = (float*)(base + 33792);
    float* rbf_sf = (float*)(base + 37376);
    int*   i_s   = (int*)(base + 38912);
    int*   j_s   = (int*)(base + 39168);

    int e0 = blockIdx.x * EB;
    int t = threadIdx.x;
    int l = t & 63;
    int wv = t >> 6;
    int g = l >> 4;     // h-group 0..3
    int er = l & 15;    // edge row in this wave's 16-edge tile

    // ---- stage W5 (32 KB), W_rbf/b_rbf, rbf tile, indices ----
    #pragma unroll
    for (int it = 0; it < 8; ++it) {
        int q = t + it * 256;
        ((uint4*)w5_s)[q] = ((const uint4*)w5f)[q];
    }
    for (int q = t; q < 7 * HIDDEN; q += 256)
        wrb_s[q] = (q < 6 * HIDDEN) ? W_rbf[q] : b_rbf[q - 6 * HIDDEN];
    for (int q = t; q < EB * NRAD + 2 * EB; q += 256) {
        if (q < EB * NRAD) {
            int gidx = e0 * NRAD + q;
            rbf_sf[q] = (gidx < n_edges * NRAD) ? rbf[gidx] : 0.f;
        } else if (q < EB * NRAD + EB) {
            int e = q - EB * NRAD;
            int ge = e0 + e;
            i_s[e] = (ge < n_edges) ? ei[ge] : 0;
        } else {
            int e = q - EB * NRAD - EB;
            int ge = e0 + e;
            j_s[e] = (ge < n_edges) ? ej[ge] : 0;
        }
    }
    __syncthreads();   // barrier 1

    // ---- issue A/B gathers (consumed only after barrier 2) ----
    int e_loc = wv * 16 + er;
    const short* ap = Abf + (size_t)i_s[e_loc] * HIDDEN + g * 4;
    const short* bp = Bbf + (size_t)j_s[e_loc] * HIDDEN + g * 4;
    uint2 avu[8], bvu[8];
    #pragma unroll
    for (int n = 0; n < 8; ++n) {
        avu[n] = *(const uint2*)(ap + n * 16);
        bvu[n] = *(const uint2*)(bp + n * 16);
    }

    // ---- phase-1: lane computes its own pfrag: P[er][kt*32 + g*8 + j] ----
    float rb[NRAD];
    #pragma unroll
    for (int r = 0; r < NRAD; ++r) rb[r] = rbf_sf[e_loc * NRAD + r];

    bf16x8 pfrag[4];
    #pragma unroll
    for (int kt = 0; kt < 4; ++kt) {
        int cb = kt * 32 + g * 8;
        f32x4 z0 = *(const f32x4*)(wrb_s + 6 * HIDDEN + cb);
        f32x4 z1 = *(const f32x4*)(wrb_s + 6 * HIDDEN + cb + 4);
        #pragma unroll
        for (int r = 0; r < NRAD; ++r) {
            z0 = fmav(rb[r], *(const f32x4*)(wrb_s + r * HIDDEN + cb), z0);
            z1 = fmav(rb[r], *(const f32x4*)(wrb_s + r * HIDDEN + cb + 4), z1);
        }
        union { bf16x8 v; unsigned int u[4]; } pu;
        pu.u[0] = pk2bf(swishf(z0[0]), swishf(z0[1]));
        pu.u[1] = pk2bf(swishf(z0[2]), swishf(z0[3]));
        pu.u[2] = pk2bf(swishf(z1[0]), swishf(z1[1]));
        pu.u[3] = pk2bf(swishf(z1[2]), swishf(z1[3]));
        pfrag[kt] = pu.v;
    }

    // ---- all 32 MFMAs (W5 from LDS: lgkmcnt only, gathers stay in flight) ----
    f32x4 acc[8];
    #pragma unroll
    for (int n = 0; n < 8; ++n) {
        f32x4 a = {0.f, 0.f, 0.f, 0.f};
        #pragma unroll
        for (int kt = 0; kt < 4; ++kt) {
            bf16x8 wfr = *(const bf16x8*)(w5_s + ((n * 4 + kt) * 64 + l) * 8);
            a = __builtin_amdgcn_mfma_f32_16x16x32_bf16(wfr, pfrag[kt], a, 0, 0, 0);
        }
        acc[n] = a;
    }
    __syncthreads();   // barrier 2: w5 region now reusable as seg buffers

    bool full = (e0 + EB <= n_edges);
    char* seg = base + wv * 8448;   // 16 rows x 528 B, wave-private

    if (full) {
        #pragma unroll
        for (int n = 0; n < 8; ++n) {
            uint2 au = avu[n], bu = bvu[n];
            f32x4 o;
            o[0] = swishf(acc[n][0] + bf2f(au.x & 0xffffu) + bf2f(bu.x & 0xffffu));
            o[1] = swishf(acc[n][1] + bf2f(au.x >> 16) + bf2f(bu.x >> 16));
            o[2] = swishf(acc[n][2] + bf2f(au.y & 0xffffu) + bf2f(bu.y & 0xffffu));
            o[3] = swishf(acc[n][3] + bf2f(au.y >> 16) + bf2f(bu.y >> 16));
            *(f32x4*)(seg + er * 528 + n * 64 + g * 16) = o;
        }
        // full-line stores: 8 rows x 128 B per instruction, conflict-free reads
        #pragma unroll
        for (int li = 0; li < 4; ++li) {
            #pragma unroll
            for (int eh = 0; eh < 2; ++eh) {
                int e = eh * 8 + (l >> 3);
                int s = l & 7;
                f32x4 v = *(const f32x4*)(seg + e * 528 + li * 128 + s * 16);
                float* dst = out + (size_t)(e0 + wv * 16 + e) * HIDDEN + li * 32 + s * 4;
                __builtin_nontemporal_store(v, (f32x4*)dst);
            }
        }
    } else {
        int ge = e0 + e_loc;
        #pragma unroll
        for (int n = 0; n < 8; ++n) {
            if (ge < n_edges) {
                uint2 au = avu[n], bu = bvu[n];
                f32x4 o;
                o[0] = swishf(acc[n][0] + bf2f(au.x & 0xffffu) + bf2f(bu.x & 0xffffu));
                o[1] = swishf(acc[n][1] + bf2f(au.x >> 16) + bf2f(bu.x >> 16));
                o[2] = swishf(acc[n][2] + bf2f(au.y & 0xffffu) + bf2f(bu.y & 0xffffu));
                o[3] = swishf(acc[n][3] + bf2f(au.y >> 16) + bf2f(bu.y >> 16));
                *(f32x4*)(out + (size_t)ge * HIDDEN + n * 16 + g * 4) = o;
            }
        }
    }
}

extern "C" void kernel_launch(void* const* d_in, const int* in_sizes, int n_in,
                              void* d_out, int out_size, void* d_ws, size_t ws_size,
                              hipStream_t stream) {
    const int*   x     = (const int*)d_in[0];
    const float* chi   = (const float*)d_in[1];
    const float* rbf   = (const float*)d_in[2];
    const int*   ei    = (const int*)d_in[3];
    const int*   ej    = (const int*)d_in[4];
    const float* emb   = (const float*)d_in[5];
    const float* W_rbf = (const float*)d_in[6];
    const float* b_rbf = (const float*)d_in[7];
    const float* W     = (const float*)d_in[8];
    const float* bvec  = (const float*)d_in[9];
    float* out = (float*)d_out;

    int n_nodes = in_sizes[0];
    int n_edges = in_sizes[3];
    int vocab   = in_sizes[5] / HIDDEN;

    short* Abf = (short*)d_ws;
    short* Bbf = Abf + (size_t)n_nodes * HIDDEN;
    float* T1  = (float*)(Bbf + (size_t)n_nodes * HIDDEN);
    float* T3  = T1 + (size_t)vocab * HIDDEN;
    short* wf  = (short*)(T3 + (size_t)vocab * HIDDEN);
    short* w2f = wf;
    short* w4f = wf + 16384;
    short* w5f = wf + 32768;

    k_emb_proj<<<vocab, HIDDEN, 0, stream>>>(emb, W, bvec, T1, T3, out + (out_size - 1));
    k_wprep<<<24, 256, 0, stream>>>(W, wf);
    k_node<<<(n_nodes + NB - 1) / NB, 256, 0, stream>>>(x, chi, w2f, w4f, T1, T3,
                                                        Abf, Bbf, n_nodes);
    k_edge<<<(n_edges + EB - 1) / EB, 256, 0, stream>>>(rbf, ei, ej, W_rbf, b_rbf,
                                                        w5f, Abf, Bbf, out, n_edges);
}

// Round 8
// 229.465 us; speedup vs baseline: 3.0199x; 1.0238x over previous
//
#include <hip/hip_runtime.h>
#include <hip/hip_bf16.h>

#define HIDDEN 128
#define NRAD 6

typedef short bf16x8 __attribute__((ext_vector_type(8)));
typedef float f32x4 __attribute__((ext_vector_type(4)));

__device__ __forceinline__ float swishf(float z) {
    return z / (1.0f + __expf(-z));
}

__device__ __forceinline__ unsigned short f2bf(float f) {
    unsigned int u = __float_as_uint(f);
    unsigned int r = (u + 0x7FFFu + ((u >> 16) & 1u)) >> 16;
    return (unsigned short)r;
}

__device__ __forceinline__ float bf2f(unsigned int s) {
    return __uint_as_float(s << 16);
}

__device__ __forceinline__ unsigned int pk2bf(float x, float y) {
    __hip_bfloat162 h = __float22bfloat162_rn(make_float2(x, y));
    return *reinterpret_cast<unsigned int*>(&h);
}

__device__ __forceinline__ f32x4 fmav(float s, f32x4 w, f32x4 z) {
    z[0] += s * w[0]; z[1] += s * w[1]; z[2] += s * w[2]; z[3] += s * w[3];
    return z;
}

// ---------------------------------------------------------------------------
// Kernel 1: T1 = emb_table @ W1 + b (bias folded), T3 = emb_table @ W3
// ---------------------------------------------------------------------------
__global__ void k_emb_proj(const float* __restrict__ emb, const float* __restrict__ W,
                           const float* __restrict__ bvec,
                           float* __restrict__ T1, float* __restrict__ T3,
                           float* __restrict__ out_scalar) {
    int v = blockIdx.x;
    int h = threadIdx.x;
    if (v == 0 && h == 0) *out_scalar = 1.0f;
    const float* er = emb + v * HIDDEN;
    float a1 = bvec[h], a3 = 0.f;
    #pragma unroll 4
    for (int k = 0; k < HIDDEN; ++k) {
        float e = er[k];
        a1 += e * W[k * HIDDEN + h];
        a3 += e * W[(256 + k) * HIDDEN + h];
    }
    T1[v * HIDDEN + h] = a1;
    T3[v * HIDDEN + h] = a3;
}

// ---------------------------------------------------------------------------
// Kernel 1b: repack W2, W4, W5 into bf16 MFMA A-operand fragments of W^T.
// ---------------------------------------------------------------------------
__global__ void k_wprep(const float* __restrict__ W, short* __restrict__ wf) {
    int gid = blockIdx.x * 256 + threadIdx.x;   // 0..6143
    int m = gid >> 11;
    int t = gid & 2047;
    int l = t & 63;
    int tile = t >> 6;
    int n = tile >> 2, kt = tile & 3;
    int k0 = kt * 32 + (l >> 4) * 8;
    int col = n * 16 + (l & 15);
    static const int rowoff[3] = {128, 384, 512};   // W2, W4, W5
    const float* Wm = W + rowoff[m] * HIDDEN;
    bf16x8 v;
    #pragma unroll
    for (int j = 0; j < 8; ++j) v[j] = (short)f2bf(Wm[(k0 + j) * HIDDEN + col]);
    *(bf16x8*)(wf + (size_t)gid * 8) = v;
}

// ---------------------------------------------------------------------------
// Kernel 2 (MFMA): A[n] = T1[x[n]] + chi[n]@W2 ; B[n] = T3[x[n]] + chi[n]@W4
// (T1 already contains bias b.)
// Abf/Bbf stored H-PERMUTED: value for h = n*16 + g*4 + j (g=0..3, n=0..7,
// j=0..3) lives at position g*32 + n*4 + j. This makes the per-edge gather in
// k_edge contiguous per lane (4 x 16B instead of 8 x 8B per matrix).
// ---------------------------------------------------------------------------
#define NB 64
__global__ __launch_bounds__(256) void k_node(const int* __restrict__ x,
        const float* __restrict__ chi,
        const short* __restrict__ w2f, const short* __restrict__ w4f,
        const float* __restrict__ T1, const float* __restrict__ T3,
        short* __restrict__ Abf, short* __restrict__ Bbf, int n_nodes) {
    __shared__ unsigned short chi_s[NB * HIDDEN];
    __shared__ int x_s[NB];
    int n0 = blockIdx.x * NB;
    int t = threadIdx.x;
    int l = t & 63;
    int wv = t >> 6;

    #pragma unroll
    for (int it = 0; it < 8; ++it) {
        int q = t + it * 256;
        int row = q >> 5, s = q & 31;
        int gn = n0 + row;
        float4 c = (gn < n_nodes) ? *(const float4*)(chi + (size_t)gn * HIDDEN + s * 4)
                                  : make_float4(0.f, 0.f, 0.f, 0.f);
        unsigned int lo = pk2bf(c.x, c.y), hi = pk2bf(c.z, c.w);
        unsigned int byte = (unsigned int)(row * 256 + s * 8) ^ ((row & 7) << 4);
        *(uint2*)((char*)chi_s + byte) = make_uint2(lo, hi);
    }
    if (t < NB) {
        int gn = n0 + t;
        x_s[t] = (gn < n_nodes) ? x[gn] : 0;
    }
    __syncthreads();

    bf16x8 cfrag[4];
    {
        int rloc = wv * 16 + (l & 15);
        unsigned int base = (unsigned int)(rloc * 256 + (l >> 4) * 16);
        unsigned int swz = (unsigned int)((rloc & 7) << 4);
        #pragma unroll
        for (int kt = 0; kt < 4; ++kt)
            cfrag[kt] = *(const bf16x8*)((const char*)chi_s + ((base + kt * 64) ^ swz));
    }

    int nd_loc = wv * 16 + (l & 15);
    int gn = n0 + nd_loc;
    int xv = x_s[nd_loc];
    int g = l >> 4;
    int hq = g * 4;
    bool live = (gn < n_nodes);
    short* arow = Abf + (size_t)gn * HIDDEN + g * 32;
    short* brow = Bbf + (size_t)gn * HIDDEN + g * 32;

    #pragma unroll
    for (int np = 0; np < 4; ++np) {        // n-pairs: n = 2*np, 2*np+1
        uint4 oa, ob;
        #pragma unroll
        for (int half = 0; half < 2; ++half) {
            int n = 2 * np + half;
            f32x4 aA = {0.f, 0.f, 0.f, 0.f};
            f32x4 aB = {0.f, 0.f, 0.f, 0.f};
            #pragma unroll
            for (int kt = 0; kt < 4; ++kt) {
                bf16x8 w2 = *(const bf16x8*)(w2f + ((size_t)(n * 4 + kt) * 64 + l) * 8);
                bf16x8 w4 = *(const bf16x8*)(w4f + ((size_t)(n * 4 + kt) * 64 + l) * 8);
                aA = __builtin_amdgcn_mfma_f32_16x16x32_bf16(w2, cfrag[kt], aA, 0, 0, 0);
                aB = __builtin_amdgcn_mfma_f32_16x16x32_bf16(w4, cfrag[kt], aB, 0, 0, 0);
            }
            if (live) {
                int h = n * 16 + hq;
                float4 t1 = *(const float4*)(T1 + (size_t)xv * HIDDEN + h);
                float4 t3 = *(const float4*)(T3 + (size_t)xv * HIDDEN + h);
                unsigned int a0 = pk2bf(aA[0] + t1.x, aA[1] + t1.y);
                unsigned int a1 = pk2bf(aA[2] + t1.z, aA[3] + t1.w);
                unsigned int b0 = pk2bf(aB[0] + t3.x, aB[1] + t3.y);
                unsigned int b1 = pk2bf(aB[2] + t3.z, aB[3] + t3.w);
                if (half == 0) { oa.x = a0; oa.y = a1; ob.x = b0; ob.y = b1; }
                else           { oa.z = a0; oa.w = a1; ob.z = b0; ob.w = b1; }
            }
        }
        if (live) {
            *(uint4*)(arow + np * 8) = oa;   // shorts g*32 + n*4 .. +7
            *(uint4*)(brow + np * 8) = ob;
        }
    }
}

// ---------------------------------------------------------------------------
// Kernel 3: 64 edges/block, 4 waves, 2 barriers.
// LDS arena (39424 B):
//   [0, 32768)      W5 fragments (bf16) -- dead after MFMA phase
//   [0, 33792)      after barrier2: per-wave seg buffers, wv*8448, 528-B rows
//   [33792, 37376)  W_rbf rows 0..5 + b_rbf
//   [37376, 38912)  rbf tile
//   [38912, 39424)  i_s, j_s
// A/B gathers: 4 x uint4 per matrix (h-permuted layout), issued after
// barrier1, consumed after barrier2 (hidden under phase-1 VALU + 32 MFMA).
// ---------------------------------------------------------------------------
#define EB 64
__global__ __launch_bounds__(256) void k_edge(const float* __restrict__ rbf,
        const int* __restrict__ ei, const int* __restrict__ ej,
        const float* __restrict__ W_rbf, const float* __restrict__ b_rbf,
        const short* __restrict__ w5f,
        const short* __restrict__ Abf, const short* __restrict__ Bbf,
        float* __restrict__ out, int n_edges) {
    __shared__ uint4 smem4[39424 / 16];
    char* base = (char*)smem4;
    short* w5_s  = (short*)base;
    float* wrb_s = (float*)(base + 33792);
    float* rbf_sf = (float*)(base + 37376);
    int*   i_s   = (int*)(base + 38912);
    int*   j_s   = (int*)(base + 39168);

    int e0 = blockIdx.x * EB;
    int t = threadIdx.x;
    int l = t & 63;
    int wv = t >> 6;
    int g = l >> 4;     // h-group 0..3
    int er = l & 15;    // edge row in this wave's 16-edge tile

    // ---- stage W5 (32 KB), W_rbf/b_rbf, rbf tile, indices ----
    #pragma unroll
    for (int it = 0; it < 8; ++it) {
        int q = t + it * 256;
        ((uint4*)w5_s)[q] = ((const uint4*)w5f)[q];
    }
    for (int q = t; q < 7 * HIDDEN; q += 256)
        wrb_s[q] = (q < 6 * HIDDEN) ? W_rbf[q] : b_rbf[q - 6 * HIDDEN];
    for (int q = t; q < EB * NRAD + 2 * EB; q += 256) {
        if (q < EB * NRAD) {
            int gidx = e0 * NRAD + q;
            rbf_sf[q] = (gidx < n_edges * NRAD) ? rbf[gidx] : 0.f;
        } else if (q < EB * NRAD + EB) {
            int e = q - EB * NRAD;
            int ge = e0 + e;
            i_s[e] = (ge < n_edges) ? ei[ge] : 0;
        } else {
            int e = q - EB * NRAD - EB;
            int ge = e0 + e;
            j_s[e] = (ge < n_edges) ? ej[ge] : 0;
        }
    }
    __syncthreads();   // barrier 1

    // ---- issue A/B gathers: 4 x 16B per matrix, contiguous per lane ----
    int e_loc = wv * 16 + er;
    const short* ap = Abf + (size_t)i_s[e_loc] * HIDDEN + g * 32;
    const short* bp = Bbf + (size_t)j_s[e_loc] * HIDDEN + g * 32;
    uint4 avq[4], bvq[4];
    #pragma unroll
    for (int q = 0; q < 4; ++q) {
        avq[q] = *(const uint4*)(ap + q * 8);
        bvq[q] = *(const uint4*)(bp + q * 8);
    }

    // ---- phase-1: lane computes its own pfrag: P[er][kt*32 + g*8 + j] ----
    float rb[NRAD];
    #pragma unroll
    for (int r = 0; r < NRAD; ++r) rb[r] = rbf_sf[e_loc * NRAD + r];

    bf16x8 pfrag[4];
    #pragma unroll
    for (int kt = 0; kt < 4; ++kt) {
        int cb = kt * 32 + g * 8;
        f32x4 z0 = *(const f32x4*)(wrb_s + 6 * HIDDEN + cb);
        f32x4 z1 = *(const f32x4*)(wrb_s + 6 * HIDDEN + cb + 4);
        #pragma unroll
        for (int r = 0; r < NRAD; ++r) {
            z0 = fmav(rb[r], *(const f32x4*)(wrb_s + r * HIDDEN + cb), z0);
            z1 = fmav(rb[r], *(const f32x4*)(wrb_s + r * HIDDEN + cb + 4), z1);
        }
        union { bf16x8 v; unsigned int u[4]; } pu;
        pu.u[0] = pk2bf(swishf(z0[0]), swishf(z0[1]));
        pu.u[1] = pk2bf(swishf(z0[2]), swishf(z0[3]));
        pu.u[2] = pk2bf(swishf(z1[0]), swishf(z1[1]));
        pu.u[3] = pk2bf(swishf(z1[2]), swishf(z1[3]));
        pfrag[kt] = pu.v;
    }

    // ---- all 32 MFMAs (W5 from LDS: lgkmcnt only, gathers stay in flight) ----
    f32x4 acc[8];
    #pragma unroll
    for (int n = 0; n < 8; ++n) {
        f32x4 a = {0.f, 0.f, 0.f, 0.f};
        #pragma unroll
        for (int kt = 0; kt < 4; ++kt) {
            bf16x8 wfr = *(const bf16x8*)(w5_s + ((n * 4 + kt) * 64 + l) * 8);
            a = __builtin_amdgcn_mfma_f32_16x16x32_bf16(wfr, pfrag[kt], a, 0, 0, 0);
        }
        acc[n] = a;
    }
    __syncthreads();   // barrier 2: w5 region now reusable as seg buffers

    bool full = (e0 + EB <= n_edges);
    char* seg = base + wv * 8448;   // 16 rows x 528 B, wave-private

    if (full) {
        #pragma unroll
        for (int n = 0; n < 8; ++n) {
            unsigned int au0 = (n & 1) ? avq[n >> 1].z : avq[n >> 1].x;
            unsigned int au1 = (n & 1) ? avq[n >> 1].w : avq[n >> 1].y;
            unsigned int bu0 = (n & 1) ? bvq[n >> 1].z : bvq[n >> 1].x;
            unsigned int bu1 = (n & 1) ? bvq[n >> 1].w : bvq[n >> 1].y;
            f32x4 o;
            o[0] = swishf(acc[n][0] + bf2f(au0 & 0xffffu) + bf2f(bu0 & 0xffffu));
            o[1] = swishf(acc[n][1] + bf2f(au0 >> 16) + bf2f(bu0 >> 16));
            o[2] = swishf(acc[n][2] + bf2f(au1 & 0xffffu) + bf2f(bu1 & 0xffffu));
            o[3] = swishf(acc[n][3] + bf2f(au1 >> 16) + bf2f(bu1 >> 16));
            *(f32x4*)(seg + er * 528 + n * 64 + g * 16) = o;
        }
        // full-line stores: 8 rows x 128 B per instruction, conflict-free reads
        #pragma unroll
        for (int li = 0; li < 4; ++li) {
            #pragma unroll
            for (int eh = 0; eh < 2; ++eh) {
                int e = eh * 8 + (l >> 3);
                int s = l & 7;
                f32x4 v = *(const f32x4*)(seg + e * 528 + li * 128 + s * 16);
                float* dst = out + (size_t)(e0 + wv * 16 + e) * HIDDEN + li * 32 + s * 4;
                __builtin_nontemporal_store(v, (f32x4*)dst);
            }
        }
    } else {
        int ge = e0 + e_loc;
        #pragma unroll
        for (int n = 0; n < 8; ++n) {
            if (ge < n_edges) {
                unsigned int au0 = (n & 1) ? avq[n >> 1].z : avq[n >> 1].x;
                unsigned int au1 = (n & 1) ? avq[n >> 1].w : avq[n >> 1].y;
                unsigned int bu0 = (n & 1) ? bvq[n >> 1].z : bvq[n >> 1].x;
                unsigned int bu1 = (n & 1) ? bvq[n >> 1].w : bvq[n >> 1].y;
                f32x4 o;
                o[0] = swishf(acc[n][0] + bf2f(au0 & 0xffffu) + bf2f(bu0 & 0xffffu));
                o[1] = swishf(acc[n][1] + bf2f(au0 >> 16) + bf2f(bu0 >> 16));
                o[2] = swishf(acc[n][2] + bf2f(au1 & 0xffffu) + bf2f(bu1 & 0xffffu));
                o[3] = swishf(acc[n][3] + bf2f(au1 >> 16) + bf2f(bu1 >> 16));
                *(f32x4*)(out + (size_t)ge * HIDDEN + n * 16 + g * 4) = o;
            }
        }
    }
}

extern "C" void kernel_launch(void* const* d_in, const int* in_sizes, int n_in,
                              void* d_out, int out_size, void* d_ws, size_t ws_size,
                              hipStream_t stream) {
    const int*   x     = (const int*)d_in[0];
    const float* chi   = (const float*)d_in[1];
    const float* rbf   = (const float*)d_in[2];
    const int*   ei    = (const int*)d_in[3];
    const int*   ej    = (const int*)d_in[4];
    const float* emb   = (const float*)d_in[5];
    const float* W_rbf = (const float*)d_in[6];
    const float* b_rbf = (const float*)d_in[7];
    const float* W     = (const float*)d_in[8];
    const float* bvec  = (const float*)d_in[9];
    float* out = (float*)d_out;

    int n_nodes = in_sizes[0];
    int n_edges = in_sizes[3];
    int vocab   = in_sizes[5] / HIDDEN;

    short* Abf = (short*)d_ws;
    short* Bbf = Abf + (size_t)n_nodes * HIDDEN;
    float* T1  = (float*)(Bbf + (size_t)n_nodes * HIDDEN);
    float* T3  = T1 + (size_t)vocab * HIDDEN;
    short* wf  = (short*)(T3 + (size_t)vocab * HIDDEN);
    short* w2f = wf;
    short* w4f = wf + 16384;
    short* w5f = wf + 32768;

    k_emb_proj<<<vocab, HIDDEN, 0, stream>>>(emb, W, bvec, T1, T3, out + (out_size - 1));
    k_wprep<<<24, 256, 0, stream>>>(W, wf);
    k_node<<<(n_nodes + NB - 1) / NB, 256, 0, stream>>>(x, chi, w2f, w4f, T1, T3,
                                                        Abf, Bbf, n_nodes);
    k_edge<<<(n_edges + EB - 1) / EB, 256, 0, stream>>>(rbf, ei, ej, W_rbf, b_rbf,
                                                        w5f, Abf, Bbf, out, n_edges);
}

// Round 9
// 210.371 us; speedup vs baseline: 3.2940x; 1.0908x over previous
//
#include <hip/hip_runtime.h>
#include <hip/hip_bf16.h>

#define HIDDEN 128
#define NRAD 6

typedef short bf16x8 __attribute__((ext_vector_type(8)));
typedef float f32x4 __attribute__((ext_vector_type(4)));

__device__ __forceinline__ float swishf(float z) {
    return z / (1.0f + __expf(-z));
}

__device__ __forceinline__ unsigned short f2bf(float f) {
    unsigned int u = __float_as_uint(f);
    unsigned int r = (u + 0x7FFFu + ((u >> 16) & 1u)) >> 16;
    return (unsigned short)r;
}

__device__ __forceinline__ float bf2f(unsigned int s) {
    return __uint_as_float(s << 16);
}

__device__ __forceinline__ unsigned int pk2bf(float x, float y) {
    __hip_bfloat162 h = __float22bfloat162_rn(make_float2(x, y));
    return *reinterpret_cast<unsigned int*>(&h);
}

// ---------------------------------------------------------------------------
// Kernel 1: T1 = emb_table @ W1 + b (bias folded), T3 = emb_table @ W3
// ---------------------------------------------------------------------------
__global__ void k_emb_proj(const float* __restrict__ emb, const float* __restrict__ W,
                           const float* __restrict__ bvec,
                           float* __restrict__ T1, float* __restrict__ T3,
                           float* __restrict__ out_scalar) {
    int v = blockIdx.x;
    int h = threadIdx.x;
    if (v == 0 && h == 0) *out_scalar = 1.0f;
    const float* er = emb + v * HIDDEN;
    float a1 = bvec[h], a3 = 0.f;
    #pragma unroll 4
    for (int k = 0; k < HIDDEN; ++k) {
        float e = er[k];
        a1 += e * W[k * HIDDEN + h];
        a3 += e * W[(256 + k) * HIDDEN + h];
    }
    T1[v * HIDDEN + h] = a1;
    T3[v * HIDDEN + h] = a3;
}

// ---------------------------------------------------------------------------
// Kernel 1b: repack weights into bf16 MFMA fragments.
//  - w2f/w4f: standard k-order W^T A-operand fragments (consumed by k_node).
//  - w5f: pi-PERMUTED k-order: slot s=g*8+j of k-tile kt holds row
//         h = 32*kt + 16*(j>>2) + 4*g + (j&3). Bijective; matches the local
//         word layout of the phase-1 MFMA output in k_edge (no shuffles).
//  - wrbf: phase-1 A-operand table: 8 n-tiles x 16 rows x 8 slots;
//         slot j<6 = W_rbf[j][h'], j==6 = b_rbf[h'] (bias via rbf slot=1.0),
//         j==7 = 0. Only the g=0 16-lane group's data is real (slots >=8 of
//         the rbf B-operand are zero, so A there is don't-care).
// ---------------------------------------------------------------------------
__global__ void k_wprep(const float* __restrict__ W,
                        const float* __restrict__ W_rbf, const float* __restrict__ b_rbf,
                        short* __restrict__ wf, short* __restrict__ wrbf) {
    int gid = blockIdx.x * 256 + threadIdx.x;
    if (gid < 4096) {                       // w2f, w4f (standard order)
        int m = gid >> 11;
        int t = gid & 2047;
        int l = t & 63;
        int tile = t >> 6;
        int n = tile >> 2, kt = tile & 3;
        int k0 = kt * 32 + (l >> 4) * 8;
        int col = n * 16 + (l & 15);
        const float* Wm = W + (m == 0 ? 128 : 384) * HIDDEN;
        bf16x8 v;
        #pragma unroll
        for (int j = 0; j < 8; ++j) v[j] = (short)f2bf(Wm[(k0 + j) * HIDDEN + col]);
        *(bf16x8*)(wf + (size_t)gid * 8) = v;
    } else if (gid < 6144) {                // w5f (pi-permuted k order)
        int t = gid - 4096;
        int l = t & 63;
        int tile = t >> 6;
        int n = tile >> 2, kt = tile & 3;
        int g = l >> 4;
        int col = n * 16 + (l & 15);
        const float* W5 = W + 512 * HIDDEN;
        bf16x8 v;
        #pragma unroll
        for (int j = 0; j < 8; ++j) {
            int hk = 32 * kt + 16 * (j >> 2) + 4 * g + (j & 3);
            v[j] = (short)f2bf(W5[hk * HIDDEN + col]);
        }
        *(bf16x8*)(wf + (size_t)gid * 8) = v;
    } else if (gid < 6272) {                // wrbf table (2 KB)
        int t2 = gid - 6144;                // 0..127
        int n = t2 >> 4, e = t2 & 15;
        int hp = n * 16 + e;
        bf16x8 v;
        #pragma unroll
        for (int j = 0; j < 8; ++j) {
            float val = (j < NRAD) ? W_rbf[j * HIDDEN + hp]
                      : (j == 6 ? b_rbf[hp] : 0.f);
            v[j] = (short)f2bf(val);
        }
        *(bf16x8*)(wrbf + (size_t)t2 * 8) = v;
    }
}

// ---------------------------------------------------------------------------
// Kernel 2 (MFMA): A[n] = T1[x[n]] + chi[n]@W2 ; B[n] = T3[x[n]] + chi[n]@W4
// Abf/Bbf stored H-PERMUTED (pos g*32+n*4+j holds h=n*16+g*4+j).
// ---------------------------------------------------------------------------
#define NB 64
__global__ __launch_bounds__(256) void k_node(const int* __restrict__ x,
        const float* __restrict__ chi,
        const short* __restrict__ w2f, const short* __restrict__ w4f,
        const float* __restrict__ T1, const float* __restrict__ T3,
        short* __restrict__ Abf, short* __restrict__ Bbf, int n_nodes) {
    __shared__ unsigned short chi_s[NB * HIDDEN];
    __shared__ int x_s[NB];
    int n0 = blockIdx.x * NB;
    int t = threadIdx.x;
    int l = t & 63;
    int wv = t >> 6;

    #pragma unroll
    for (int it = 0; it < 8; ++it) {
        int q = t + it * 256;
        int row = q >> 5, s = q & 31;
        int gn = n0 + row;
        float4 c = (gn < n_nodes) ? *(const float4*)(chi + (size_t)gn * HIDDEN + s * 4)
                                  : make_float4(0.f, 0.f, 0.f, 0.f);
        unsigned int lo = pk2bf(c.x, c.y), hi = pk2bf(c.z, c.w);
        unsigned int byte = (unsigned int)(row * 256 + s * 8) ^ ((row & 7) << 4);
        *(uint2*)((char*)chi_s + byte) = make_uint2(lo, hi);
    }
    if (t < NB) {
        int gn = n0 + t;
        x_s[t] = (gn < n_nodes) ? x[gn] : 0;
    }
    __syncthreads();

    bf16x8 cfrag[4];
    {
        int rloc = wv * 16 + (l & 15);
        unsigned int base = (unsigned int)(rloc * 256 + (l >> 4) * 16);
        unsigned int swz = (unsigned int)((rloc & 7) << 4);
        #pragma unroll
        for (int kt = 0; kt < 4; ++kt)
            cfrag[kt] = *(const bf16x8*)((const char*)chi_s + ((base + kt * 64) ^ swz));
    }

    int nd_loc = wv * 16 + (l & 15);
    int gn = n0 + nd_loc;
    int xv = x_s[nd_loc];
    int g = l >> 4;
    int hq = g * 4;
    bool live = (gn < n_nodes);
    short* arow = Abf + (size_t)gn * HIDDEN + g * 32;
    short* brow = Bbf + (size_t)gn * HIDDEN + g * 32;

    #pragma unroll
    for (int np = 0; np < 4; ++np) {
        uint4 oa, ob;
        #pragma unroll
        for (int half = 0; half < 2; ++half) {
            int n = 2 * np + half;
            f32x4 aA = {0.f, 0.f, 0.f, 0.f};
            f32x4 aB = {0.f, 0.f, 0.f, 0.f};
            #pragma unroll
            for (int kt = 0; kt < 4; ++kt) {
                bf16x8 w2 = *(const bf16x8*)(w2f + ((size_t)(n * 4 + kt) * 64 + l) * 8);
                bf16x8 w4 = *(const bf16x8*)(w4f + ((size_t)(n * 4 + kt) * 64 + l) * 8);
                aA = __builtin_amdgcn_mfma_f32_16x16x32_bf16(w2, cfrag[kt], aA, 0, 0, 0);
                aB = __builtin_amdgcn_mfma_f32_16x16x32_bf16(w4, cfrag[kt], aB, 0, 0, 0);
            }
            if (live) {
                int h = n * 16 + hq;
                float4 t1 = *(const float4*)(T1 + (size_t)xv * HIDDEN + h);
                float4 t3 = *(const float4*)(T3 + (size_t)xv * HIDDEN + h);
                unsigned int a0 = pk2bf(aA[0] + t1.x, aA[1] + t1.y);
                unsigned int a1 = pk2bf(aA[2] + t1.z, aA[3] + t1.w);
                unsigned int b0 = pk2bf(aB[0] + t3.x, aB[1] + t3.y);
                unsigned int b1 = pk2bf(aB[2] + t3.z, aB[3] + t3.w);
                if (half == 0) { oa.x = a0; oa.y = a1; ob.x = b0; ob.y = b1; }
                else           { oa.z = a0; oa.w = a1; ob.z = b0; ob.w = b1; }
            }
        }
        if (live) {
            *(uint4*)(arow + np * 8) = oa;
            *(uint4*)(brow + np * 8) = ob;
        }
    }
}

// ---------------------------------------------------------------------------
// Kernel 3: 64 edges/block, 4 waves, 2 barriers. Phase-1 is now an MFMA
// (K=6 padded to 32; slot 6 = 1.0 carries the bias), output words are
// locally reassembled into pfrag thanks to w5f's pi-permuted k-order.
// LDS arena (36096 B, 4 blocks/CU):
//   [0, 32768)      w5_s (pi-packed W5 fragments) -- dead after MFMAs
//   [0, 33792)      after barrier2: per-wave seg buffers (wv*8448, 528-B rows)
//   [32768, 34816)  wrbf_s (phase-1 A-operand table, 2 KB) -- dead after ph-1
//   [34816, 35584)  rbf_b (64 x 6 bf16)
//   [35584, 36096)  i_s, j_s
// ---------------------------------------------------------------------------
#define EB 64
__global__ __launch_bounds__(256) void k_edge(const float* __restrict__ rbf,
        const int* __restrict__ ei, const int* __restrict__ ej,
        const short* __restrict__ w5f, const short* __restrict__ wrbf,
        const short* __restrict__ Abf, const short* __restrict__ Bbf,
        float* __restrict__ out, int n_edges) {
    __shared__ uint4 smem4[36096 / 16];
    char* base = (char*)smem4;
    short* w5_s   = (short*)base;
    short* wrbf_s = (short*)(base + 32768);
    unsigned short* rbf_b = (unsigned short*)(base + 34816);
    int*   i_s    = (int*)(base + 35584);
    int*   j_s    = (int*)(base + 35840);

    int e0 = blockIdx.x * EB;
    int t = threadIdx.x;
    int l = t & 63;
    int wv = t >> 6;
    int g = l >> 4;     // h-group / k-slot group
    int er = l & 15;    // edge row within this wave's 16-edge tile

    // ---- stage w5 (32 KB), wrbf (2 KB), rbf->bf16, indices ----
    #pragma unroll
    for (int it = 0; it < 8; ++it) {
        int q = t + it * 256;
        ((uint4*)w5_s)[q] = ((const uint4*)w5f)[q];
    }
    if (t < 128) ((uint4*)wrbf_s)[t] = ((const uint4*)wrbf)[t];
    #pragma unroll
    for (int it = 0; it < 2; ++it) {
        int q = t + it * 256;
        if (q < EB * NRAD) {
            int gidx = e0 * NRAD + q;
            rbf_b[q] = (gidx < n_edges * NRAD) ? f2bf(rbf[gidx]) : (unsigned short)0;
        } else if (q < EB * NRAD + EB) {
            int e = q - EB * NRAD;
            int ge = e0 + e;
            i_s[e] = (ge < n_edges) ? ei[ge] : 0;
        } else {
            int e = q - EB * NRAD - EB;
            int ge = e0 + e;
            j_s[e] = (ge < n_edges) ? ej[ge] : 0;
        }
    }
    __syncthreads();   // barrier 1

    // ---- issue A/B gathers (vmcnt untouched until epilogue) ----
    int e_loc = wv * 16 + er;
    const short* ap = Abf + (size_t)i_s[e_loc] * HIDDEN + g * 32;
    const short* bp = Bbf + (size_t)j_s[e_loc] * HIDDEN + g * 32;
    uint4 avq[4], bvq[4];
    #pragma unroll
    for (int q = 0; q < 4; ++q) {
        avq[q] = *(const uint4*)(ap + q * 8);
        bvq[q] = *(const uint4*)(bp + q * 8);
    }

    // ---- phase-1 via MFMA: rbf0_raw[h'][e] = sum_k WrbfT[h'][k] * rbf_pad[k][e]
    union { bf16x8 v; unsigned int u[4]; } rbfrag;
    {
        const char* rp = (const char*)rbf_b + e_loc * 12;
        unsigned int q0 = *(const unsigned int*)(rp);
        unsigned int q1 = *(const unsigned int*)(rp + 4);
        unsigned int q2 = *(const unsigned int*)(rp + 8);
        bool g0 = (g == 0);
        rbfrag.u[0] = g0 ? q0 : 0u;
        rbfrag.u[1] = g0 ? q1 : 0u;
        rbfrag.u[2] = g0 ? q2 : 0u;
        rbfrag.u[3] = g0 ? 0x00003F80u : 0u;   // slot6 = 1.0 (bias), slot7 = 0
    }
    f32x4 accp[8];
    #pragma unroll
    for (int n = 0; n < 8; ++n) {
        bf16x8 wa = *(const bf16x8*)(wrbf_s + (n * 16 + er) * 8);
        f32x4 z = {0.f, 0.f, 0.f, 0.f};
        accp[n] = __builtin_amdgcn_mfma_f32_16x16x32_bf16(wa, rbfrag.v, z, 0, 0, 0);
    }
    // swish + pack; lane holds rows 4g..4g+3 of each 16-row tile n
    unsigned int word0[8], word1[8];
    #pragma unroll
    for (int n = 0; n < 8; ++n) {
        float s0 = swishf(accp[n][0]), s1 = swishf(accp[n][1]);
        float s2 = swishf(accp[n][2]), s3 = swishf(accp[n][3]);
        word0[n] = pk2bf(s0, s1);
        word1[n] = pk2bf(s2, s3);
    }
    bf16x8 pfrag[4];
    #pragma unroll
    for (int kt = 0; kt < 4; ++kt) {
        union { bf16x8 v; unsigned int u[4]; } pu;
        pu.u[0] = word0[2 * kt];
        pu.u[1] = word1[2 * kt];
        pu.u[2] = word0[2 * kt + 1];
        pu.u[3] = word1[2 * kt + 1];
        pfrag[kt] = pu.v;
    }

    // ---- main MFMAs: W5 (pi-packed) from LDS; gathers stay in flight ----
    f32x4 acc[8];
    #pragma unroll
    for (int n = 0; n < 8; ++n) {
        f32x4 a = {0.f, 0.f, 0.f, 0.f};
        #pragma unroll
        for (int kt = 0; kt < 4; ++kt) {
            bf16x8 wfr = *(const bf16x8*)(w5_s + ((n * 4 + kt) * 64 + l) * 8);
            a = __builtin_amdgcn_mfma_f32_16x16x32_bf16(wfr, pfrag[kt], a, 0, 0, 0);
        }
        acc[n] = a;
    }
    __syncthreads();   // barrier 2: w5/wrbf regions now reusable as seg

    bool full = (e0 + EB <= n_edges);
    char* seg = base + wv * 8448;   // 16 rows x 528 B, wave-private

    if (full) {
        #pragma unroll
        for (int n = 0; n < 8; ++n) {
            unsigned int au0 = (n & 1) ? avq[n >> 1].z : avq[n >> 1].x;
            unsigned int au1 = (n & 1) ? avq[n >> 1].w : avq[n >> 1].y;
            unsigned int bu0 = (n & 1) ? bvq[n >> 1].z : bvq[n >> 1].x;
            unsigned int bu1 = (n & 1) ? bvq[n >> 1].w : bvq[n >> 1].y;
            f32x4 o;
            o[0] = swishf(acc[n][0] + bf2f(au0 & 0xffffu) + bf2f(bu0 & 0xffffu));
            o[1] = swishf(acc[n][1] + bf2f(au0 >> 16) + bf2f(bu0 >> 16));
            o[2] = swishf(acc[n][2] + bf2f(au1 & 0xffffu) + bf2f(bu1 & 0xffffu));
            o[3] = swishf(acc[n][3] + bf2f(au1 >> 16) + bf2f(bu1 >> 16));
            *(f32x4*)(seg + er * 528 + n * 64 + g * 16) = o;
        }
        #pragma unroll
        for (int li = 0; li < 4; ++li) {
            #pragma unroll
            for (int eh = 0; eh < 2; ++eh) {
                int e = eh * 8 + (l >> 3);
                int s = l & 7;
                f32x4 v = *(const f32x4*)(seg + e * 528 + li * 128 + s * 16);
                float* dst = out + (size_t)(e0 + wv * 16 + e) * HIDDEN + li * 32 + s * 4;
                __builtin_nontemporal_store(v, (f32x4*)dst);
            }
        }
    } else {
        int ge = e0 + e_loc;
        #pragma unroll
        for (int n = 0; n < 8; ++n) {
            if (ge < n_edges) {
                unsigned int au0 = (n & 1) ? avq[n >> 1].z : avq[n >> 1].x;
                unsigned int au1 = (n & 1) ? avq[n >> 1].w : avq[n >> 1].y;
                unsigned int bu0 = (n & 1) ? bvq[n >> 1].z : bvq[n >> 1].x;
                unsigned int bu1 = (n & 1) ? bvq[n >> 1].w : bvq[n >> 1].y;
                f32x4 o;
                o[0] = swishf(acc[n][0] + bf2f(au0 & 0xffffu) + bf2f(bu0 & 0xffffu));
                o[1] = swishf(acc[n][1] + bf2f(au0 >> 16) + bf2f(bu0 >> 16));
                o[2] = swishf(acc[n][2] + bf2f(au1 & 0xffffu) + bf2f(bu1 & 0xffffu));
                o[3] = swishf(acc[n][3] + bf2f(au1 >> 16) + bf2f(bu1 >> 16));
                *(f32x4*)(out + (size_t)ge * HIDDEN + n * 16 + g * 4) = o;
            }
        }
    }
}

extern "C" void kernel_launch(void* const* d_in, const int* in_sizes, int n_in,
                              void* d_out, int out_size, void* d_ws, size_t ws_size,
                              hipStream_t stream) {
    const int*   x     = (const int*)d_in[0];
    const float* chi   = (const float*)d_in[1];
    const float* rbf   = (const float*)d_in[2];
    const int*   ei    = (const int*)d_in[3];
    const int*   ej    = (const int*)d_in[4];
    const float* emb   = (const float*)d_in[5];
    const float* W_rbf = (const float*)d_in[6];
    const float* b_rbf = (const float*)d_in[7];
    const float* W     = (const float*)d_in[8];
    const float* bvec  = (const float*)d_in[9];
    float* out = (float*)d_out;

    int n_nodes = in_sizes[0];
    int n_edges = in_sizes[3];
    int vocab   = in_sizes[5] / HIDDEN;

    short* Abf = (short*)d_ws;
    short* Bbf = Abf + (size_t)n_nodes * HIDDEN;
    float* T1  = (float*)(Bbf + (size_t)n_nodes * HIDDEN);
    float* T3  = T1 + (size_t)vocab * HIDDEN;
    short* wf  = (short*)(T3 + (size_t)vocab * HIDDEN);
    short* w2f = wf;
    short* w4f = wf + 16384;
    short* w5f = wf + 32768;
    short* wrbf = wf + 49152;   // 1024 shorts

    k_emb_proj<<<vocab, HIDDEN, 0, stream>>>(emb, W, bvec, T1, T3, out + (out_size - 1));
    k_wprep<<<25, 256, 0, stream>>>(W, W_rbf, b_rbf, wf, wrbf);
    k_node<<<(n_nodes + NB - 1) / NB, 256, 0, stream>>>(x, chi, w2f, w4f, T1, T3,
                                                        Abf, Bbf, n_nodes);
    k_edge<<<(n_edges + EB - 1) / EB, 256, 0, stream>>>(rbf, ei, ej, w5f, wrbf,
                                                        Abf, Bbf, out, n_edges);
}